// Round 11
// baseline (1030.618 us; speedup 1.0000x reference)
//
#include <hip/hip_runtime.h>

#define N_NODES 50000
#define N_EDGES 800000
#define D 128

// ---------------- graph build ----------------

__global__ void deg_kernel(const int* __restrict__ dst, int* __restrict__ deg) {
  int e = blockIdx.x * 256 + threadIdx.x;
  if (e < N_EDGES) atomicAdd(&deg[dst[e]], 1);
}

// single-block scan (1024 thr = 16 waves), wave-shuffle based:
// exclusive prefix over deg -> row_start (+ cursor copy), plus inv = 1/(deg+1)
__global__ void scan_kernel(const int* __restrict__ deg, int* __restrict__ row_start,
                            int* __restrict__ cursor, float* __restrict__ inv) {
  __shared__ int wsum[16];
  __shared__ int carry_s;
  const int t = threadIdx.x;
  const int lane = t & 63, wid = t >> 6;
  if (t == 0) carry_s = 0;
  __syncthreads();
  for (int base = 0; base < N_NODES; base += 4096) {
    int i0 = base + t * 4;
    int v[4];
    int s = 0;
#pragma unroll
    for (int j = 0; j < 4; ++j) {
      int i = i0 + j;
      v[j] = (i < N_NODES) ? deg[i] : 0;
      s += v[j];
    }
    // wave-inclusive scan of s
    int run = s;
#pragma unroll
    for (int off = 1; off < 64; off <<= 1) {
      int o = __shfl_up(run, off);
      if (lane >= off) run += o;
    }
    if (lane == 63) wsum[wid] = run;
    __syncthreads();
    if (t < 16) {
      int w = wsum[t];
#pragma unroll
      for (int off = 1; off < 16; off <<= 1) {
        int o = __shfl_up(w, off, 16);
        if (t >= off) w += o;
      }
      wsum[t] = w;  // inclusive over wave sums
    }
    __syncthreads();
    int excl = carry_s + (wid ? wsum[wid - 1] : 0) + run - s;
#pragma unroll
    for (int j = 0; j < 4; ++j) {
      int i = i0 + j;
      if (i < N_NODES) {
        row_start[i] = excl;
        cursor[i] = excl;
        inv[i] = 1.0f / (float)(v[j] + 1);
      }
      excl += v[j];
    }
    __syncthreads();
    if (t == 0) carry_s += wsum[15];
    __syncthreads();
  }
  if (t == 0) row_start[N_NODES] = carry_s;
}

__global__ void csr_kernel(const int* __restrict__ src, const int* __restrict__ dst,
                           int* __restrict__ cursor, int* __restrict__ csr) {
  int e = blockIdx.x * 256 + threadIdx.x;
  if (e < N_EDGES) {
    int p = atomicAdd(&cursor[dst[e]], 1);  // cursor pre-seeded with row_start
    csr[p] = src[e];
  }
}

// transpose the three weight matrices into ws: wT[k][o] = W[o][k]
__global__ void wtrans_kernel(const float* __restrict__ W1, const float* __restrict__ W2,
                              const float* __restrict__ W3, float* __restrict__ wT) {
  int g = blockIdx.x * 256 + threadIdx.x;
  if (g < 16384) {
    int k = g >> 7, o = g & 127;
    wT[g] = W1[o * 128 + k];
  } else if (g < 32768) {
    int l = g - 16384;
    int k = l >> 7, o = l & 127;
    wT[g] = W2[o * 128 + k];
  } else if (g < 40960) {
    int l = g - 32768;
    int k = l >> 6, o = l & 63;
    wT[g] = W3[o * 128 + k];
  }
}

// ---------------- per-layer kernels ----------------

// CSR gather over DV-dim rows: out[n] = relu?( (G[n] + sum_nbr G[nbr]) * inv[n] )
// BW-bound at ~3.7 TB/s (measured r4/r5/r8: ILP 4->8 and occupancy 68->58%
// both leave time at ~58.5us); FETCH ~186MB = 8 XCDs x compulsory table fill.
template <int DV, bool RELU>
__global__ __launch_bounds__(256) void agg_kernel(const float* __restrict__ G,
    const int* __restrict__ row_start, const int* __restrict__ csr,
    const float* __restrict__ inv, float* __restrict__ outA) {
  constexpr int L = DV / 4;    // lanes per row
  constexpr int NPW = 64 / L;  // nodes per wave
  const int wave = (blockIdx.x * 256 + threadIdx.x) >> 6;
  const int lane = threadIdx.x & 63;
  const int sub = lane / L;
  const int li = lane % L;
  const int node = wave * NPW + sub;

  const float4* hp = (const float4*)G;
  float4 acc = hp[(size_t)node * L + li];
  float4 acc2 = make_float4(0.f, 0.f, 0.f, 0.f);
  const int s = row_start[node], e = row_start[node + 1];
  int j = s;
  for (; j + 8 <= e; j += 8) {
    int n0 = csr[j + 0], n1 = csr[j + 1], n2 = csr[j + 2], n3 = csr[j + 3];
    int n4 = csr[j + 4], n5 = csr[j + 5], n6 = csr[j + 6], n7 = csr[j + 7];
    float4 v0 = hp[(size_t)n0 * L + li];
    float4 v1 = hp[(size_t)n1 * L + li];
    float4 v2 = hp[(size_t)n2 * L + li];
    float4 v3 = hp[(size_t)n3 * L + li];
    float4 v4 = hp[(size_t)n4 * L + li];
    float4 v5 = hp[(size_t)n5 * L + li];
    float4 v6 = hp[(size_t)n6 * L + li];
    float4 v7 = hp[(size_t)n7 * L + li];
    acc.x  += (v0.x + v1.x) + (v2.x + v3.x);
    acc.y  += (v0.y + v1.y) + (v2.y + v3.y);
    acc.z  += (v0.z + v1.z) + (v2.z + v3.z);
    acc.w  += (v0.w + v1.w) + (v2.w + v3.w);
    acc2.x += (v4.x + v5.x) + (v6.x + v7.x);
    acc2.y += (v4.y + v5.y) + (v6.y + v7.y);
    acc2.z += (v4.z + v5.z) + (v6.z + v7.z);
    acc2.w += (v4.w + v5.w) + (v6.w + v7.w);
  }
  for (; j + 4 <= e; j += 4) {
    int n0 = csr[j + 0], n1 = csr[j + 1], n2 = csr[j + 2], n3 = csr[j + 3];
    float4 v0 = hp[(size_t)n0 * L + li];
    float4 v1 = hp[(size_t)n1 * L + li];
    float4 v2 = hp[(size_t)n2 * L + li];
    float4 v3 = hp[(size_t)n3 * L + li];
    acc.x += (v0.x + v1.x) + (v2.x + v3.x);
    acc.y += (v0.y + v1.y) + (v2.y + v3.y);
    acc.z += (v0.z + v1.z) + (v2.z + v3.z);
    acc.w += (v0.w + v1.w) + (v2.w + v3.w);
  }
  for (; j < e; ++j) {
    int nb = csr[j];
    float4 v = hp[(size_t)nb * L + li];
    acc2.x += v.x; acc2.y += v.y; acc2.z += v.z; acc2.w += v.w;
  }
  acc.x += acc2.x; acc.y += acc2.y; acc.z += acc2.z; acc.w += acc2.w;
  float iv = inv[node];
  acc.x *= iv; acc.y *= iv; acc.z *= iv; acc.w *= iv;
  if (RELU) {
    acc.x = fmaxf(acc.x, 0.f); acc.y = fmaxf(acc.y, 0.f);
    acc.z = fmaxf(acc.z, 0.f); acc.w = fmaxf(acc.w, 0.f);
  }
  ((float4*)outA)[(size_t)node * L + li] = acc;
}

// f32 GEMM: out[r][o] = A[r][:] . wT[:][o], A: [N][128], wT: [128][DOUT]
// r8 lesson: BM=128 -> 391 blocks on 256 CUs = 1.5/CU -> 2x tail + 1 wave/SIMD
// (no latency hiding). Now BM=64 -> 782 blocks (3.05/CU), LDS 48KB -> 3
// blocks/CU. Thread tile 4 rows x TO (TO=DOUT/16), thread's outs strided:
// {outT*4 + j4*64} so W-reads are 16B-stride across 16 lanes = 2-way (free),
// A-reads 2-way via kb^(rowT>>1) swizzle. Per kb: 6 b128 (~72cy) vs 128
// FMA-instr (256cy) -> VALU-bound 3.5:1.
// rule #20 guard: fragment scalars via named components ONLY (r7 spill: 1.6GB).
template <int DOUT>
__global__ __launch_bounds__(256, 3) void gemm_kernel(const float* __restrict__ A,
    const float* __restrict__ wT, float* __restrict__ out) {
  constexpr int TO = DOUT / 16;    // outs per thread (8 or 4)
  constexpr int NJ4 = TO / 4;      // j4 groups (2 or 1), each 4 outs, stride 64
  __shared__ float aL[64 * 64];    // [row][k4 ^ (row>>3) : 4]  (16 KB)
  __shared__ float wL[64 * DOUT];  // [k][o], per-kt half        (32/16 KB)
  const int t = threadIdx.x;
  const int row0 = blockIdx.x * 64;

  const int rowT = t >> 4;   // 0..15 (4 rows each)
  const int outT = t & 15;   // 0..15 (TO outs each, strided by 64)

  const float4* A4 = (const float4*)A;
  const float4* w4 = (const float4*)wT;
  float4* aL4 = (float4*)aL;
  float4* wL4 = (float4*)wL;
  const float4* aL4c = (const float4*)aL;
  const float4* wL4c = (const float4*)wL;

  float acc[4][TO];
#pragma unroll
  for (int i = 0; i < 4; ++i)
#pragma unroll
    for (int j = 0; j < TO; ++j) acc[i][j] = 0.f;

// one dk-step: extract a[i].COMP (named component — no address-taking)
#define DK_STEP(COMP, DK)                                                   \
  {                                                                         \
    _Pragma("unroll")                                                       \
    for (int j4 = 0; j4 < NJ4; ++j4) {                                      \
      float4 b = wL4c[(kb * 4 + (DK)) * (DOUT / 4) + outT + j4 * 16];       \
      _Pragma("unroll")                                                     \
      for (int i = 0; i < 4; ++i) {                                         \
        float av = a[i].COMP;                                               \
        acc[i][j4 * 4 + 0] += av * b.x;                                     \
        acc[i][j4 * 4 + 1] += av * b.y;                                     \
        acc[i][j4 * 4 + 2] += av * b.z;                                     \
        acc[i][j4 * 4 + 3] += av * b.w;                                     \
      }                                                                     \
    }                                                                       \
  }

#pragma unroll
  for (int kt = 0; kt < 2; ++kt) {
    if (kt) __syncthreads();
    // stage A: 64 rows x 16 float4 (cols kt*64..+63)
#pragma unroll
    for (int i = 0; i < 4; ++i) {
      int g4 = t + i * 256;      // 0..1023
      int r = g4 >> 4;           // 0..63
      int k4 = g4 & 15;
      int gr = row0 + r;
      float4 v = make_float4(0.f, 0.f, 0.f, 0.f);
      if (gr < N_NODES) v = A4[(size_t)gr * 32 + kt * 16 + k4];
      aL4[r * 16 + (k4 ^ ((r >> 3) & 7))] = v;
    }
    // stage W: 64 k x DOUT/4 float4 (linear copy, conflict-free)
#pragma unroll
    for (int i = 0; i < TO; ++i) {
      int g4 = t + i * 256;            // 0..64*DOUT/4-1
      int k = g4 / (DOUT / 4);
      int o4 = g4 % (DOUT / 4);
      wL4[k * (DOUT / 4) + o4] = w4[(size_t)(kt * 64 + k) * (DOUT / 4) + o4];
    }
    __syncthreads();

    for (int kb = 0; kb < 16; ++kb) {
      float4 a[4];
#pragma unroll
      for (int i = 0; i < 4; ++i)
        a[i] = aL4c[(rowT * 4 + i) * 16 + (kb ^ ((rowT >> 1) & 7))];
      DK_STEP(x, 0)
      DK_STEP(y, 1)
      DK_STEP(z, 2)
      DK_STEP(w, 3)
    }
  }
#undef DK_STEP

#pragma unroll
  for (int i = 0; i < 4; ++i) {
    int gr = row0 + rowT * 4 + i;
    if (gr < N_NODES) {
#pragma unroll
      for (int j4 = 0; j4 < NJ4; ++j4) {
        float4 v = make_float4(acc[i][j4 * 4 + 0], acc[i][j4 * 4 + 1],
                               acc[i][j4 * 4 + 2], acc[i][j4 * 4 + 3]);
        *(float4*)&out[(size_t)gr * DOUT + outT * 4 + j4 * 64] = v;
      }
    }
  }
}

// ---------------- launch ----------------

extern "C" void kernel_launch(void* const* d_in, const int* in_sizes, int n_in,
                              void* d_out, int out_size, void* d_ws, size_t ws_size,
                              hipStream_t stream) {
  const float* x  = (const float*)d_in[0];
  const int* ei   = (const int*)d_in[1];
  const float* W1 = (const float*)d_in[2];
  const float* W2 = (const float*)d_in[3];
  const float* W3 = (const float*)d_in[4];
  const int* src = ei;
  const int* dst = ei + N_EDGES;
  float* out = (float*)d_out;

  // workspace layout (256B-aligned chunks)
  char* ws = (char*)d_ws;
  size_t off = 0;
  auto alloc = [&](size_t bytes) {
    void* p = ws + off;
    off += (bytes + 255) & ~(size_t)255;
    return p;
  };
  int* deg       = (int*)alloc(N_NODES * sizeof(int));
  int* row_start = (int*)alloc((N_NODES + 1) * sizeof(int));
  int* cursor    = (int*)alloc(N_NODES * sizeof(int));
  int* csr       = (int*)alloc(N_EDGES * sizeof(int));
  float* inv     = (float*)alloc(N_NODES * sizeof(float));
  float* wT      = (float*)alloc((16384 + 16384 + 8192) * sizeof(float));
  float* G       = (float*)alloc((size_t)N_NODES * D * sizeof(float));
  float* H       = (float*)alloc((size_t)N_NODES * D * sizeof(float));
  (void)ws_size;

  float* wT1 = wT;
  float* wT2 = wT + 16384;
  float* wT3 = wT + 32768;

  hipMemsetAsync(deg, 0, N_NODES * sizeof(int), stream);

  const int eblocks = (N_EDGES + 255) / 256;
  deg_kernel<<<eblocks, 256, 0, stream>>>(dst, deg);
  scan_kernel<<<1, 1024, 0, stream>>>(deg, row_start, cursor, inv);
  csr_kernel<<<eblocks, 256, 0, stream>>>(src, dst, cursor, csr);
  wtrans_kernel<<<(40960 + 255) / 256, 256, 0, stream>>>(W1, W2, W3, wT);

  const int gblocks = (N_NODES + 63) / 64;  // 782 (3.05 blocks/CU)

  // layer l: G = h @ Wl^T, then h' = relu(agg(G))   [agg and GEMM commute]
  // layer 1: x -> G -> H
  gemm_kernel<128><<<gblocks, 256, 0, stream>>>(x, wT1, G);
  agg_kernel<128, true><<<6250, 256, 0, stream>>>(G, row_start, csr, inv, H);
  // layer 2: H -> G -> H
  gemm_kernel<128><<<gblocks, 256, 0, stream>>>(H, wT2, G);
  agg_kernel<128, true><<<6250, 256, 0, stream>>>(G, row_start, csr, inv, H);
  // layer 3: H -> G(64) -> out (final relu fused into agg)
  gemm_kernel<64><<<gblocks, 256, 0, stream>>>(H, wT3, G);
  agg_kernel<64, true><<<3125, 256, 0, stream>>>(G, row_start, csr, inv, out);
}

// Round 13
// 446.811 us; speedup vs baseline: 2.3066x; 2.3066x over previous
//
#include <hip/hip_runtime.h>

#define N_NODES 50000
#define N_EDGES 800000
#define D 128

// ---------------- graph build ----------------

// fused: blocks [0,3124] do degree histogram; blocks [3125,3284] transpose W1/W2/W3
__global__ void deg_wtrans_kernel(const int* __restrict__ dst, int* __restrict__ deg,
                                  const float* __restrict__ W1, const float* __restrict__ W2,
                                  const float* __restrict__ W3, float* __restrict__ wT) {
  int b = blockIdx.x;
  if (b < 3125) {
    int e = b * 256 + threadIdx.x;
    if (e < N_EDGES) atomicAdd(&deg[dst[e]], 1);
  } else {
    int g = (b - 3125) * 256 + threadIdx.x;
    if (g < 16384) {
      int k = g >> 7, o = g & 127;
      wT[g] = W1[o * 128 + k];
    } else if (g < 32768) {
      int l = g - 16384;
      int k = l >> 7, o = l & 127;
      wT[g] = W2[o * 128 + k];
    } else if (g < 40960) {
      int l = g - 32768;
      int k = l >> 6, o = l & 63;
      wT[g] = W3[o * 128 + k];
    }
  }
}

// single-block scan (1024 thr = 16 waves), wave-shuffle based:
// exclusive prefix over deg -> row_start (+ cursor copy), plus inv = 1/(deg+1)
__global__ void scan_kernel(const int* __restrict__ deg, int* __restrict__ row_start,
                            int* __restrict__ cursor, float* __restrict__ inv) {
  __shared__ int wsum[16];
  __shared__ int carry_s;
  const int t = threadIdx.x;
  const int lane = t & 63, wid = t >> 6;
  if (t == 0) carry_s = 0;
  __syncthreads();
  for (int base = 0; base < N_NODES; base += 4096) {
    int i0 = base + t * 4;
    int v[4];
    int s = 0;
#pragma unroll
    for (int j = 0; j < 4; ++j) {
      int i = i0 + j;
      v[j] = (i < N_NODES) ? deg[i] : 0;
      s += v[j];
    }
    // wave-inclusive scan of s
    int run = s;
#pragma unroll
    for (int off = 1; off < 64; off <<= 1) {
      int o = __shfl_up(run, off);
      if (lane >= off) run += o;
    }
    if (lane == 63) wsum[wid] = run;
    __syncthreads();
    if (t < 16) {
      int w = wsum[t];
#pragma unroll
      for (int off = 1; off < 16; off <<= 1) {
        int o = __shfl_up(w, off, 16);
        if (t >= off) w += o;
      }
      wsum[t] = w;  // inclusive over wave sums
    }
    __syncthreads();
    int excl = carry_s + (wid ? wsum[wid - 1] : 0) + run - s;
#pragma unroll
    for (int j = 0; j < 4; ++j) {
      int i = i0 + j;
      if (i < N_NODES) {
        row_start[i] = excl;
        cursor[i] = excl;
        inv[i] = 1.0f / (float)(v[j] + 1);
      }
      excl += v[j];
    }
    __syncthreads();
    if (t == 0) carry_s += wsum[15];
    __syncthreads();
  }
  if (t == 0) row_start[N_NODES] = carry_s;
}

__global__ void csr_kernel(const int* __restrict__ src, const int* __restrict__ dst,
                           int* __restrict__ cursor, int* __restrict__ csr) {
  int e = blockIdx.x * 256 + threadIdx.x;
  if (e < N_EDGES) {
    int p = atomicAdd(&cursor[dst[e]], 1);  // cursor pre-seeded with row_start
    csr[p] = src[e];
  }
}

// ---------------- per-layer kernels ----------------

// CSR gather over DV-dim rows: out[n] = relu?( (G[n] + sum_nbr G[nbr]) * inv[n] )
// BW-bound at ~3.7 TB/s (measured r4/r5/r8: ILP 4->8 and occupancy 68->58%
// both leave time at ~58.5us); FETCH ~186MB = 8 XCDs x compulsory table fill.
template <int DV, bool RELU>
__global__ __launch_bounds__(256) void agg_kernel(const float* __restrict__ G,
    const int* __restrict__ row_start, const int* __restrict__ csr,
    const float* __restrict__ inv, float* __restrict__ outA) {
  constexpr int L = DV / 4;    // lanes per row
  constexpr int NPW = 64 / L;  // nodes per wave
  const int wave = (blockIdx.x * 256 + threadIdx.x) >> 6;
  const int lane = threadIdx.x & 63;
  const int sub = lane / L;
  const int li = lane % L;
  const int node = wave * NPW + sub;

  const float4* hp = (const float4*)G;
  float4 acc = hp[(size_t)node * L + li];
  float4 acc2 = make_float4(0.f, 0.f, 0.f, 0.f);
  const int s = row_start[node], e = row_start[node + 1];
  int j = s;
  for (; j + 8 <= e; j += 8) {
    int n0 = csr[j + 0], n1 = csr[j + 1], n2 = csr[j + 2], n3 = csr[j + 3];
    int n4 = csr[j + 4], n5 = csr[j + 5], n6 = csr[j + 6], n7 = csr[j + 7];
    float4 v0 = hp[(size_t)n0 * L + li];
    float4 v1 = hp[(size_t)n1 * L + li];
    float4 v2 = hp[(size_t)n2 * L + li];
    float4 v3 = hp[(size_t)n3 * L + li];
    float4 v4 = hp[(size_t)n4 * L + li];
    float4 v5 = hp[(size_t)n5 * L + li];
    float4 v6 = hp[(size_t)n6 * L + li];
    float4 v7 = hp[(size_t)n7 * L + li];
    acc.x  += (v0.x + v1.x) + (v2.x + v3.x);
    acc.y  += (v0.y + v1.y) + (v2.y + v3.y);
    acc.z  += (v0.z + v1.z) + (v2.z + v3.z);
    acc.w  += (v0.w + v1.w) + (v2.w + v3.w);
    acc2.x += (v4.x + v5.x) + (v6.x + v7.x);
    acc2.y += (v4.y + v5.y) + (v6.y + v7.y);
    acc2.z += (v4.z + v5.z) + (v6.z + v7.z);
    acc2.w += (v4.w + v5.w) + (v6.w + v7.w);
  }
  for (; j + 4 <= e; j += 4) {
    int n0 = csr[j + 0], n1 = csr[j + 1], n2 = csr[j + 2], n3 = csr[j + 3];
    float4 v0 = hp[(size_t)n0 * L + li];
    float4 v1 = hp[(size_t)n1 * L + li];
    float4 v2 = hp[(size_t)n2 * L + li];
    float4 v3 = hp[(size_t)n3 * L + li];
    acc.x += (v0.x + v1.x) + (v2.x + v3.x);
    acc.y += (v0.y + v1.y) + (v2.y + v3.y);
    acc.z += (v0.z + v1.z) + (v2.z + v3.z);
    acc.w += (v0.w + v1.w) + (v2.w + v3.w);
  }
  for (; j < e; ++j) {
    int nb = csr[j];
    float4 v = hp[(size_t)nb * L + li];
    acc2.x += v.x; acc2.y += v.y; acc2.z += v.z; acc2.w += v.w;
  }
  acc.x += acc2.x; acc.y += acc2.y; acc.z += acc2.z; acc.w += acc2.w;
  float iv = inv[node];
  acc.x *= iv; acc.y *= iv; acc.z *= iv; acc.w *= iv;
  if (RELU) {
    acc.x = fmaxf(acc.x, 0.f); acc.y = fmaxf(acc.y, 0.f);
    acc.z = fmaxf(acc.z, 0.f); acc.w = fmaxf(acc.w, 0.f);
  }
  ((float4*)outA)[(size_t)node * L + li] = acc;
}

// f32 GEMM: out[r][o] = A[r][:] . wT[:][o], A: [N][128], wT: [128][DOUT]
// PROVEN round-8-measured version (total 440us) — do not perturb.
// Block: 128 rows x DOUT outs, 256 threads, thread tile 8 x TO (TO=DOUT/16),
// K staged in 2 tiles of 64. Wave = 8 rowT x 8 outT.
// rule #20 guard: fragment scalars via named components ONLY (r7: address-
// taking spilled 1.6GB). r11 lesson: BM=64 + strided outs + LB(256,3)
// triggered array demotion to scratch (VGPR 84, FETCH 890MB, 619us) —
// keep THIS exact structure.
template <int DOUT>
__global__ __launch_bounds__(256, 2) void gemm_kernel(const float* __restrict__ A,
    const float* __restrict__ wT, float* __restrict__ out) {
  constexpr int TO = DOUT / 16;  // outs per thread (8 or 4)
  __shared__ float aL[128 * 64];   // [row][k4 ^ (row>>3) : 4]  (32 KB)
  __shared__ float wL[64 * DOUT];  // [k][o]                    (32/16 KB)
  const int t = threadIdx.x;
  const int row0 = blockIdx.x * 128;

  // lane mapping: wave = 8 rowT x 8 outT
  const int w = t >> 6, l = t & 63;
  const int rowT = (l >> 3) + ((w >> 1) << 3);  // 0..15
  const int outT = (l & 7) + ((w & 1) << 3);    // 0..15

  const float4* A4 = (const float4*)A;
  const float4* w4 = (const float4*)wT;
  float4* aL4 = (float4*)aL;
  float4* wL4 = (float4*)wL;
  const float4* aL4c = (const float4*)aL;
  const float4* wL4c = (const float4*)wL;

  float acc[8][TO];
#pragma unroll
  for (int i = 0; i < 8; ++i)
#pragma unroll
    for (int j = 0; j < TO; ++j) acc[i][j] = 0.f;

// one dk-step: extract a[i].COMP (named component — no address-taking)
#define DK_STEP(COMP, DK)                                                  \
  {                                                                        \
    _Pragma("unroll")                                                      \
    for (int j4 = 0; j4 < TO / 4; ++j4) {                                  \
      float4 b = wL4c[(kb * 4 + (DK)) * (DOUT / 4) + outT * (TO / 4) + j4];\
      _Pragma("unroll")                                                    \
      for (int i = 0; i < 8; ++i) {                                        \
        float av = a[i].COMP;                                              \
        acc[i][j4 * 4 + 0] += av * b.x;                                    \
        acc[i][j4 * 4 + 1] += av * b.y;                                    \
        acc[i][j4 * 4 + 2] += av * b.z;                                    \
        acc[i][j4 * 4 + 3] += av * b.w;                                    \
      }                                                                    \
    }                                                                      \
  }

#pragma unroll
  for (int kt = 0; kt < 2; ++kt) {
    if (kt) __syncthreads();
    // stage A: 128 rows x 16 float4 (cols kt*64..+63)
#pragma unroll
    for (int i = 0; i < 8; ++i) {
      int g4 = t + i * 256;      // 0..2047
      int r = g4 >> 4;           // 0..127
      int k4 = g4 & 15;
      int gr = row0 + r;
      float4 v = make_float4(0.f, 0.f, 0.f, 0.f);
      if (gr < N_NODES) v = A4[(size_t)gr * 32 + kt * 16 + k4];
      aL4[r * 16 + (k4 ^ ((r >> 3) & 15))] = v;
    }
    // stage W: 64 k x DOUT/4 float4
#pragma unroll
    for (int i = 0; i < TO; ++i) {
      int g4 = t + i * 256;            // 0..64*DOUT/4-1
      int k = g4 / (DOUT / 4);
      int o4 = g4 % (DOUT / 4);
      wL4[k * (DOUT / 4) + o4] = w4[(size_t)(kt * 64 + k) * (DOUT / 4) + o4];
    }
    __syncthreads();

    for (int kb = 0; kb < 16; ++kb) {
      float4 a[8];
#pragma unroll
      for (int i = 0; i < 8; ++i)
        a[i] = aL4c[(rowT * 8 + i) * 16 + (kb ^ rowT)];
      DK_STEP(x, 0)
      DK_STEP(y, 1)
      DK_STEP(z, 2)
      DK_STEP(w, 3)
    }
  }
#undef DK_STEP

#pragma unroll
  for (int i = 0; i < 8; ++i) {
    int gr = row0 + rowT * 8 + i;
    if (gr < N_NODES) {
#pragma unroll
      for (int j4 = 0; j4 < TO / 4; ++j4) {
        float4 v = make_float4(acc[i][j4 * 4 + 0], acc[i][j4 * 4 + 1],
                               acc[i][j4 * 4 + 2], acc[i][j4 * 4 + 3]);
        *(float4*)&out[(size_t)gr * DOUT + outT * TO + j4 * 4] = v;
      }
    }
  }
}

// ---------------- launch ----------------

extern "C" void kernel_launch(void* const* d_in, const int* in_sizes, int n_in,
                              void* d_out, int out_size, void* d_ws, size_t ws_size,
                              hipStream_t stream) {
  const float* x  = (const float*)d_in[0];
  const int* ei   = (const int*)d_in[1];
  const float* W1 = (const float*)d_in[2];
  const float* W2 = (const float*)d_in[3];
  const float* W3 = (const float*)d_in[4];
  const int* src = ei;
  const int* dst = ei + N_EDGES;
  float* out = (float*)d_out;

  // workspace layout (256B-aligned chunks)
  char* ws = (char*)d_ws;
  size_t off = 0;
  auto alloc = [&](size_t bytes) {
    void* p = ws + off;
    off += (bytes + 255) & ~(size_t)255;
    return p;
  };
  int* deg       = (int*)alloc(N_NODES * sizeof(int));
  int* row_start = (int*)alloc((N_NODES + 1) * sizeof(int));
  int* cursor    = (int*)alloc(N_NODES * sizeof(int));
  int* csr       = (int*)alloc(N_EDGES * sizeof(int));
  float* inv     = (float*)alloc(N_NODES * sizeof(float));
  float* wT      = (float*)alloc((16384 + 16384 + 8192) * sizeof(float));
  float* G       = (float*)alloc((size_t)N_NODES * D * sizeof(float));
  float* H       = (float*)alloc((size_t)N_NODES * D * sizeof(float));
  (void)ws_size;

  float* wT1 = wT;
  float* wT2 = wT + 16384;
  float* wT3 = wT + 32768;

  hipMemsetAsync(deg, 0, N_NODES * sizeof(int), stream);

  const int eblocks = (N_EDGES + 255) / 256;  // 3125
  deg_wtrans_kernel<<<eblocks + 160, 256, 0, stream>>>(dst, deg, W1, W2, W3, wT);
  scan_kernel<<<1, 1024, 0, stream>>>(deg, row_start, cursor, inv);
  csr_kernel<<<eblocks, 256, 0, stream>>>(src, dst, cursor, csr);

  const int gblocks = (N_NODES + 127) / 128;  // 391

  // layer l: G = h @ Wl^T, then h' = relu(agg(G))   [agg and GEMM commute]
  // layer 1: x -> G -> H
  gemm_kernel<128><<<gblocks, 256, 0, stream>>>(x, wT1, G);
  agg_kernel<128, true><<<6250, 256, 0, stream>>>(G, row_start, csr, inv, H);
  // layer 2: H -> G -> H
  gemm_kernel<128><<<gblocks, 256, 0, stream>>>(H, wT2, G);
  agg_kernel<128, true><<<6250, 256, 0, stream>>>(G, row_start, csr, inv, H);
  // layer 3: H -> G(64) -> out (final relu fused into agg)
  gemm_kernel<64><<<gblocks, 256, 0, stream>>>(H, wT3, G);
  agg_kernel<64, true><<<3125, 256, 0, stream>>>(G, row_start, csr, inv, out);
}

// Round 16
// 390.039 us; speedup vs baseline: 2.6423x; 1.1456x over previous
//
#include <hip/hip_runtime.h>

#define N_NODES 50000
#define N_EDGES 800000
#define D 128

// ---------------- fused: gemm1 + degree + wtrans(W2,W3) ----------------
// blocks [0,390]: layer-1 GEMM G = x @ W1^T (W1 transposed on the fly;
//   inner loop is a VERBATIM copy of the proven r8 gemm structure)
// blocks [391,3515]: degree histogram
// blocks [3516,3611]: transpose W2,W3 into wT+16384 / wT+32768
__global__ __launch_bounds__(256, 2) void fused_gemm1_kernel(
    const float* __restrict__ x, const float* __restrict__ W1,
    const int* __restrict__ dst, int* __restrict__ deg,
    const float* __restrict__ W2, const float* __restrict__ W3,
    float* __restrict__ wT, float* __restrict__ G) {
  __shared__ float aL[128 * 64];   // 32 KB
  __shared__ float wL[64 * 128];   // 32 KB
  const int b = blockIdx.x;
  const int t = threadIdx.x;

  if (b < 391) {
    const int row0 = b * 128;
    const int w = t >> 6, l = t & 63;
    const int rowT = (l >> 3) + ((w >> 1) << 3);  // 0..15
    const int outT = (l & 7) + ((w & 1) << 3);    // 0..15

    const float4* A4 = (const float4*)x;
    float4* aL4 = (float4*)aL;
    float4* wL4 = (float4*)wL;
    const float4* aL4c = (const float4*)aL;
    const float4* wL4c = (const float4*)wL;

    float acc[8][8];
#pragma unroll
    for (int i = 0; i < 8; ++i)
#pragma unroll
      for (int j = 0; j < 8; ++j) acc[i][j] = 0.f;

#define DK_STEP1(COMP, DK)                                              \
  {                                                                     \
    _Pragma("unroll")                                                   \
    for (int j4 = 0; j4 < 2; ++j4) {                                    \
      float4 bb = wL4c[(kb * 4 + (DK)) * 32 + outT * 2 + j4];           \
      _Pragma("unroll")                                                 \
      for (int i = 0; i < 8; ++i) {                                     \
        float av = a[i].COMP;                                           \
        acc[i][j4 * 4 + 0] += av * bb.x;                                \
        acc[i][j4 * 4 + 1] += av * bb.y;                                \
        acc[i][j4 * 4 + 2] += av * bb.z;                                \
        acc[i][j4 * 4 + 3] += av * bb.w;                                \
      }                                                                 \
    }                                                                   \
  }

#pragma unroll
    for (int kt = 0; kt < 2; ++kt) {
      if (kt) __syncthreads();
      // stage A: 128 rows x 16 float4 (cols kt*64..+63)
#pragma unroll
      for (int i = 0; i < 8; ++i) {
        int g4 = t + i * 256;
        int r = g4 >> 4;
        int k4 = g4 & 15;
        int gr = row0 + r;
        float4 v = make_float4(0.f, 0.f, 0.f, 0.f);
        if (gr < N_NODES) v = A4[(size_t)gr * 32 + kt * 16 + k4];
        aL4[r * 16 + (k4 ^ ((r >> 3) & 15))] = v;
      }
      // stage W from W1 transposed: wL[k][o] = W1[o*128 + kt*64+k]
#pragma unroll
      for (int i = 0; i < 8; ++i) {
        int g4 = t + i * 256;    // 0..2047 over 64 k x 32 o4
        int k = g4 >> 5;
        int o4 = g4 & 31;
        int kk = kt * 64 + k;
        int o = o4 * 4;
        float4 v = make_float4(W1[(o + 0) * 128 + kk], W1[(o + 1) * 128 + kk],
                               W1[(o + 2) * 128 + kk], W1[(o + 3) * 128 + kk]);
        wL4[k * 32 + o4] = v;
      }
      __syncthreads();

      for (int kb = 0; kb < 16; ++kb) {
        float4 a[8];
#pragma unroll
        for (int i = 0; i < 8; ++i)
          a[i] = aL4c[(rowT * 8 + i) * 16 + (kb ^ rowT)];
        DK_STEP1(x, 0)
        DK_STEP1(y, 1)
        DK_STEP1(z, 2)
        DK_STEP1(w, 3)
      }
    }
#undef DK_STEP1

#pragma unroll
    for (int i = 0; i < 8; ++i) {
      int gr = row0 + rowT * 8 + i;
      if (gr < N_NODES) {
#pragma unroll
        for (int j4 = 0; j4 < 2; ++j4) {
          float4 v = make_float4(acc[i][j4 * 4 + 0], acc[i][j4 * 4 + 1],
                                 acc[i][j4 * 4 + 2], acc[i][j4 * 4 + 3]);
          *(float4*)&G[(size_t)gr * 128 + outT * 8 + j4 * 4] = v;
        }
      }
    }
  } else if (b < 3516) {
    int e = (b - 391) * 256 + t;
    if (e < N_EDGES) atomicAdd(&deg[dst[e]], 1);
  } else {
    int g = (b - 3516) * 256 + t;
    if (g < 16384) {
      int k = g >> 7, o = g & 127;
      wT[16384 + g] = W2[o * 128 + k];
    } else if (g < 24576) {
      int l = g - 16384;
      int k = l >> 6, o = l & 63;
      wT[32768 + l] = W3[o * 128 + k];
    }
  }
}

// ---------------- graph build ----------------

// one-pass scan: 1024 threads x 52 contiguous elems (13 int4) each.
// thread-local sum -> wave scan -> 16-partial scan -> int4 prefix writeback.
// ~4 barriers total (old 13-tile version: ~170 barrier/shfl rounds, serial).
__global__ void scan_kernel(const int* __restrict__ deg, int* __restrict__ row_start,
                            int* __restrict__ cursor, float* __restrict__ inv) {
  __shared__ int wsum[16];
  const int t = threadIdx.x;            // 1024
  const int lane = t & 63, wid = t >> 6;
  const int i0 = t * 52;
  const int4* d4 = (const int4*)deg;
  int s = 0;
  if (i0 + 52 <= N_NODES) {
#pragma unroll
    for (int j = 0; j < 13; ++j) {
      int4 v = d4[i0 / 4 + j];
      s += (v.x + v.y) + (v.z + v.w);
    }
  } else {
    for (int i = i0; i < N_NODES; ++i) s += deg[i];
  }
  int run = s;
#pragma unroll
  for (int off = 1; off < 64; off <<= 1) {
    int o = __shfl_up(run, off);
    if (lane >= off) run += o;
  }
  if (lane == 63) wsum[wid] = run;
  __syncthreads();
  if (t < 16) {
    int w = wsum[t];
#pragma unroll
    for (int off = 1; off < 16; off <<= 1) {
      int o = __shfl_up(w, off, 16);
      if (t >= off) w += o;
    }
    wsum[t] = w;
  }
  __syncthreads();
  int excl = (wid ? wsum[wid - 1] : 0) + run - s;
  if (i0 + 52 <= N_NODES) {
#pragma unroll
    for (int j = 0; j < 13; ++j) {
      int4 v = d4[i0 / 4 + j];
      int e0 = excl, e1 = e0 + v.x, e2 = e1 + v.y, e3 = e2 + v.z;
      ((int4*)row_start)[i0 / 4 + j] = make_int4(e0, e1, e2, e3);
      ((int4*)cursor)[i0 / 4 + j] = make_int4(e0, e1, e2, e3);
      ((float4*)inv)[i0 / 4 + j] =
          make_float4(1.f / (float)(v.x + 1), 1.f / (float)(v.y + 1),
                      1.f / (float)(v.z + 1), 1.f / (float)(v.w + 1));
      excl = e3 + v.w;
    }
  } else {
    for (int i = i0; i < N_NODES; ++i) {
      int d = deg[i];
      row_start[i] = excl;
      cursor[i] = excl;
      inv[i] = 1.f / (float)(d + 1);
      excl += d;
    }
  }
  if (t == 1023) row_start[N_NODES] = excl;
}

__global__ void csr_kernel(const int* __restrict__ src, const int* __restrict__ dst,
                           int* __restrict__ cursor, int* __restrict__ csr) {
  int e = blockIdx.x * 256 + threadIdx.x;
  if (e < N_EDGES) {
    int p = atomicAdd(&cursor[dst[e]], 1);  // cursor pre-seeded with row_start
    csr[p] = src[e];
  }
}

// ---------------- per-layer kernels ----------------

// CSR gather over DV-dim rows: out[n] = relu?( (G[n] + sum_nbr G[nbr]) * inv[n] )
// BW-bound at ~3.7 TB/s (measured r4/r5/r8/r13); FETCH ~186MB = 8 XCDs x
// compulsory table fill — irreducible for pull-based gather.
template <int DV, bool RELU>
__global__ __launch_bounds__(256) void agg_kernel(const float* __restrict__ G,
    const int* __restrict__ row_start, const int* __restrict__ csr,
    const float* __restrict__ inv, float* __restrict__ outA) {
  constexpr int L = DV / 4;    // lanes per row
  constexpr int NPW = 64 / L;  // nodes per wave
  const int wave = (blockIdx.x * 256 + threadIdx.x) >> 6;
  const int lane = threadIdx.x & 63;
  const int sub = lane / L;
  const int li = lane % L;
  const int node = wave * NPW + sub;

  const float4* hp = (const float4*)G;
  float4 acc = hp[(size_t)node * L + li];
  float4 acc2 = make_float4(0.f, 0.f, 0.f, 0.f);
  const int s = row_start[node], e = row_start[node + 1];
  int j = s;
  for (; j + 8 <= e; j += 8) {
    int n0 = csr[j + 0], n1 = csr[j + 1], n2 = csr[j + 2], n3 = csr[j + 3];
    int n4 = csr[j + 4], n5 = csr[j + 5], n6 = csr[j + 6], n7 = csr[j + 7];
    float4 v0 = hp[(size_t)n0 * L + li];
    float4 v1 = hp[(size_t)n1 * L + li];
    float4 v2 = hp[(size_t)n2 * L + li];
    float4 v3 = hp[(size_t)n3 * L + li];
    float4 v4 = hp[(size_t)n4 * L + li];
    float4 v5 = hp[(size_t)n5 * L + li];
    float4 v6 = hp[(size_t)n6 * L + li];
    float4 v7 = hp[(size_t)n7 * L + li];
    acc.x  += (v0.x + v1.x) + (v2.x + v3.x);
    acc.y  += (v0.y + v1.y) + (v2.y + v3.y);
    acc.z  += (v0.z + v1.z) + (v2.z + v3.z);
    acc.w  += (v0.w + v1.w) + (v2.w + v3.w);
    acc2.x += (v4.x + v5.x) + (v6.x + v7.x);
    acc2.y += (v4.y + v5.y) + (v6.y + v7.y);
    acc2.z += (v4.z + v5.z) + (v6.z + v7.z);
    acc2.w += (v4.w + v5.w) + (v6.w + v7.w);
  }
  for (; j + 4 <= e; j += 4) {
    int n0 = csr[j + 0], n1 = csr[j + 1], n2 = csr[j + 2], n3 = csr[j + 3];
    float4 v0 = hp[(size_t)n0 * L + li];
    float4 v1 = hp[(size_t)n1 * L + li];
    float4 v2 = hp[(size_t)n2 * L + li];
    float4 v3 = hp[(size_t)n3 * L + li];
    acc.x += (v0.x + v1.x) + (v2.x + v3.x);
    acc.y += (v0.y + v1.y) + (v2.y + v3.y);
    acc.z += (v0.z + v1.z) + (v2.z + v3.z);
    acc.w += (v0.w + v1.w) + (v2.w + v3.w);
  }
  for (; j < e; ++j) {
    int nb = csr[j];
    float4 v = hp[(size_t)nb * L + li];
    acc2.x += v.x; acc2.y += v.y; acc2.z += v.z; acc2.w += v.w;
  }
  acc.x += acc2.x; acc.y += acc2.y; acc.z += acc2.z; acc.w += acc2.w;
  float iv = inv[node];
  acc.x *= iv; acc.y *= iv; acc.z *= iv; acc.w *= iv;
  if (RELU) {
    acc.x = fmaxf(acc.x, 0.f); acc.y = fmaxf(acc.y, 0.f);
    acc.z = fmaxf(acc.z, 0.f); acc.w = fmaxf(acc.w, 0.f);
  }
  ((float4*)outA)[(size_t)node * L + li] = acc;
}

// f32 GEMM: out[r][o] = A[r][:] . wT[:][o], A: [N][128], wT: [128][DOUT]
// PROVEN round-8-measured version (total 440us) — do not perturb.
// rule #20 guard: fragment scalars via named components ONLY (r7: address-
// taking spilled 1.6GB). r11 lesson: BM=64 + strided outs + LB(256,3)
// triggered array demotion to scratch — keep THIS exact structure.
template <int DOUT>
__global__ __launch_bounds__(256, 2) void gemm_kernel(const float* __restrict__ A,
    const float* __restrict__ wT, float* __restrict__ out) {
  constexpr int TO = DOUT / 16;  // outs per thread (8 or 4)
  __shared__ float aL[128 * 64];   // [row][k4 ^ (row>>3) : 4]  (32 KB)
  __shared__ float wL[64 * DOUT];  // [k][o]                    (32/16 KB)
  const int t = threadIdx.x;
  const int row0 = blockIdx.x * 128;

  // lane mapping: wave = 8 rowT x 8 outT
  const int w = t >> 6, l = t & 63;
  const int rowT = (l >> 3) + ((w >> 1) << 3);  // 0..15
  const int outT = (l & 7) + ((w & 1) << 3);    // 0..15

  const float4* A4 = (const float4*)A;
  const float4* w4 = (const float4*)wT;
  float4* aL4 = (float4*)aL;
  float4* wL4 = (float4*)wL;
  const float4* aL4c = (const float4*)aL;
  const float4* wL4c = (const float4*)wL;

  float acc[8][TO];
#pragma unroll
  for (int i = 0; i < 8; ++i)
#pragma unroll
    for (int j = 0; j < TO; ++j) acc[i][j] = 0.f;

// one dk-step: extract a[i].COMP (named component — no address-taking)
#define DK_STEP(COMP, DK)                                                  \
  {                                                                        \
    _Pragma("unroll")                                                      \
    for (int j4 = 0; j4 < TO / 4; ++j4) {                                  \
      float4 b = wL4c[(kb * 4 + (DK)) * (DOUT / 4) + outT * (TO / 4) + j4];\
      _Pragma("unroll")                                                    \
      for (int i = 0; i < 8; ++i) {                                        \
        float av = a[i].COMP;                                              \
        acc[i][j4 * 4 + 0] += av * b.x;                                    \
        acc[i][j4 * 4 + 1] += av * b.y;                                    \
        acc[i][j4 * 4 + 2] += av * b.z;                                    \
        acc[i][j4 * 4 + 3] += av * b.w;                                    \
      }                                                                    \
    }                                                                      \
  }

#pragma unroll
  for (int kt = 0; kt < 2; ++kt) {
    if (kt) __syncthreads();
    // stage A: 128 rows x 16 float4 (cols kt*64..+63)
#pragma unroll
    for (int i = 0; i < 8; ++i) {
      int g4 = t + i * 256;      // 0..2047
      int r = g4 >> 4;           // 0..127
      int k4 = g4 & 15;
      int gr = row0 + r;
      float4 v = make_float4(0.f, 0.f, 0.f, 0.f);
      if (gr < N_NODES) v = A4[(size_t)gr * 32 + kt * 16 + k4];
      aL4[r * 16 + (k4 ^ ((r >> 3) & 15))] = v;
    }
    // stage W: 64 k x DOUT/4 float4
#pragma unroll
    for (int i = 0; i < TO; ++i) {
      int g4 = t + i * 256;            // 0..64*DOUT/4-1
      int k = g4 / (DOUT / 4);
      int o4 = g4 % (DOUT / 4);
      wL4[k * (DOUT / 4) + o4] = w4[(size_t)(kt * 64 + k) * (DOUT / 4) + o4];
    }
    __syncthreads();

    for (int kb = 0; kb < 16; ++kb) {
      float4 a[8];
#pragma unroll
      for (int i = 0; i < 8; ++i)
        a[i] = aL4c[(rowT * 8 + i) * 16 + (kb ^ rowT)];
      DK_STEP(x, 0)
      DK_STEP(y, 1)
      DK_STEP(z, 2)
      DK_STEP(w, 3)
    }
  }
#undef DK_STEP

#pragma unroll
  for (int i = 0; i < 8; ++i) {
    int gr = row0 + rowT * 8 + i;
    if (gr < N_NODES) {
#pragma unroll
      for (int j4 = 0; j4 < TO / 4; ++j4) {
        float4 v = make_float4(acc[i][j4 * 4 + 0], acc[i][j4 * 4 + 1],
                               acc[i][j4 * 4 + 2], acc[i][j4 * 4 + 3]);
        *(float4*)&out[(size_t)gr * DOUT + outT * TO + j4 * 4] = v;
      }
    }
  }
}

// ---------------- launch ----------------

extern "C" void kernel_launch(void* const* d_in, const int* in_sizes, int n_in,
                              void* d_out, int out_size, void* d_ws, size_t ws_size,
                              hipStream_t stream) {
  const float* x  = (const float*)d_in[0];
  const int* ei   = (const int*)d_in[1];
  const float* W1 = (const float*)d_in[2];
  const float* W2 = (const float*)d_in[3];
  const float* W3 = (const float*)d_in[4];
  const int* src = ei;
  const int* dst = ei + N_EDGES;
  float* out = (float*)d_out;

  // workspace layout (256B-aligned chunks)
  char* ws = (char*)d_ws;
  size_t off = 0;
  auto alloc = [&](size_t bytes) {
    void* p = ws + off;
    off += (bytes + 255) & ~(size_t)255;
    return p;
  };
  int* deg       = (int*)alloc(N_NODES * sizeof(int));
  int* row_start = (int*)alloc((N_NODES + 1) * sizeof(int));
  int* cursor    = (int*)alloc(N_NODES * sizeof(int));
  int* csr       = (int*)alloc(N_EDGES * sizeof(int));
  float* inv     = (float*)alloc(N_NODES * sizeof(float));
  float* wT      = (float*)alloc((16384 + 16384 + 8192) * sizeof(float));
  float* G       = (float*)alloc((size_t)N_NODES * D * sizeof(float));
  float* H       = (float*)alloc((size_t)N_NODES * D * sizeof(float));
  (void)ws_size;

  float* wT2 = wT + 16384;
  float* wT3 = wT + 32768;

  hipMemsetAsync(deg, 0, N_NODES * sizeof(int), stream);

  const int eblocks = (N_EDGES + 255) / 256;  // 3125
  // gemm1 (391) + deg (3125) + wtrans W2/W3 (96) in one launch
  fused_gemm1_kernel<<<391 + eblocks + 96, 256, 0, stream>>>(
      x, W1, dst, deg, W2, W3, wT, G);
  scan_kernel<<<1, 1024, 0, stream>>>(deg, row_start, cursor, inv);
  csr_kernel<<<eblocks, 256, 0, stream>>>(src, dst, cursor, csr);

  const int gblocks = (N_NODES + 127) / 128;  // 391

  // layer 1: G ready from fused kernel -> H
  agg_kernel<128, true><<<6250, 256, 0, stream>>>(G, row_start, csr, inv, H);
  // layer 2: H -> G -> H
  gemm_kernel<128><<<gblocks, 256, 0, stream>>>(H, wT2, G);
  agg_kernel<128, true><<<6250, 256, 0, stream>>>(G, row_start, csr, inv, H);
  // layer 3: H -> G(64) -> out (final relu fused into agg)
  gemm_kernel<64><<<gblocks, 256, 0, stream>>>(H, wT3, G);
  agg_kernel<64, true><<<3125, 256, 0, stream>>>(G, row_start, csr, inv, out);
}